// Round 7
// baseline (226.192 us; speedup 1.0000x reference)
//
#include <hip/hip_runtime.h>
#include <stdint.h>

// GINConv1d: B=4, N=8192, K=16, C_IN=C_OUT=128
//
// R6 finding: the gather phase (~15-20 us) is INVARIANT across occupancy,
// prefetch, and kernel structure -> L1-miss line-processing bound (1.1M cache
// lines @ ~2-4 cyc/line/CU). Remaining addressable cost = kernel boundaries.
// R7: single kernel. cvt(x->bf16) and gather+MFMA phases separated by a
// grid-wide monotonic-epoch barrier (device-global counter; each launch adds
// exactly GRID so no reset is needed across graph replays). grid=512 =
// 2 blocks/CU exactly co-resident under launch_bounds(256,2).
#define BATCH   4
#define NNODE   8192
#define KNBR    16
#define CIN     128
#define COUT    128
#define THREADS 256
#define GRID    512         // 2 blocks/CU x 256 CU - all co-resident
#define HS_STRIDE 136       // shorts per LDS row: 128 + 8 pad

#define XELEM   (BATCH * NNODE * CIN)          // 4194304 elements

typedef __attribute__((ext_vector_type(8))) short short8;   // 8 bf16 (MFMA A/B frag)
typedef __attribute__((ext_vector_type(4))) float f32x4;
typedef __attribute__((ext_vector_type(4))) int   i32x4;

__device__ __forceinline__ short bf16_rne(float f) {
    union { float f; uint32_t u; } v; v.f = f;
    return (short)((v.u + 0x7FFFu + ((v.u >> 16) & 1u)) >> 16);  // round-to-nearest-even
}
__device__ __forceinline__ float bf16_f32(short s) {
    union { uint32_t u; float f; } v; v.u = ((uint32_t)(uint16_t)s) << 16;
    return v.f;
}

// Monotonic grid-barrier counter. Zero-init at module load; each launch adds
// exactly GRID, so epoch arithmetic works across unlimited graph replays.
__device__ unsigned long long g_bar;

__global__ __launch_bounds__(THREADS, 2)
void gin_mono(const float* __restrict__ x,      // [B,N,CIN] fp32
              const int*   __restrict__ eidx,   // [2,B,N,K] int32; plane 0 = src idx
              const float* __restrict__ W,      // [COUT,CIN] fp32
              const float* __restrict__ bias,   // [COUT]
              const float* __restrict__ epsp,   // [1]
              ushort*      __restrict__ xb,     // ws: [B,N,CIN] bf16
              float*       __restrict__ out)    // [B,N,COUT] fp32
{
    __shared__ __align__(16) short h_s[32 * HS_STRIDE];

    const int tid  = threadIdx.x;
    const int i    = blockIdx.x;           // 0..511
    const int xcd  = i & 7;                // XCD round-robin pin
    const int sub  = i >> 3;               // 0..63
    const int b    = xcd >> 1;             // batch 0..3 pinned to XCD pair
    const int half = xcd & 1;
    const int chunk = half * 64 + sub;     // 0..127: 64-row slice of batch b

    // ---------------- Phase 0: convert own 64-row slice of batch b ----------------
    {
        const size_t base = ((size_t)b * NNODE + (size_t)chunk * 64) * CIN; // 8192 elems
        const float*  xs = x  + base + tid * 32;
        ushort*       xd = xb + base + tid * 32;
        #pragma unroll
        for (int g = 0; g < 4; ++g) {
            f32x4 a = __builtin_nontemporal_load((const f32x4*)(xs + g * 8));
            f32x4 c = __builtin_nontemporal_load((const f32x4*)(xs + g * 8 + 4));
            short8 s;
            s[0]=bf16_rne(a[0]); s[1]=bf16_rne(a[1]); s[2]=bf16_rne(a[2]); s[3]=bf16_rne(a[3]);
            s[4]=bf16_rne(c[0]); s[5]=bf16_rne(c[1]); s[6]=bf16_rne(c[2]); s[7]=bf16_rne(c[3]);
            *(short8*)(xd + g * 8) = s;
        }
    }

    // ---------------- W -> bf16 B-fragments (overlaps other blocks' cvt) ----------
    const int wave = tid >> 6;
    const int lane = tid & 63;
    const int l16  = lane & 15;
    const int lq   = lane >> 4;            // quad 0..3

    short8 bfrag[2][4];                    // [o_tile][kb]: B[k][n]=W[o][c], n=l16, k=lq*8+j
    #pragma unroll
    for (int t = 0; t < 2; ++t) {
        const float* wp = W + (size_t)(wave * 32 + t * 16 + l16) * CIN;
        #pragma unroll
        for (int kb = 0; kb < 4; ++kb) {
            const float* wq = wp + kb * 32 + lq * 8;
            f32x4 f0 = *(const f32x4*)(wq);
            f32x4 f1 = *(const f32x4*)(wq + 4);
            short8 s;
            s[0]=bf16_rne(f0[0]); s[1]=bf16_rne(f0[1]); s[2]=bf16_rne(f0[2]); s[3]=bf16_rne(f0[3]);
            s[4]=bf16_rne(f1[0]); s[5]=bf16_rne(f1[1]); s[6]=bf16_rne(f1[2]); s[7]=bf16_rne(f1[3]);
            bfrag[t][kb] = s;
        }
    }
    const float bias0 = bias[wave * 32 + l16];
    const float bias1 = bias[wave * 32 + 16 + l16];
    const float eps1  = 1.0f + epsp[0];

    // ---------------- grid-wide barrier (monotonic epoch, cross-XCD fences) -------
    __threadfence();                       // release: each thread's xb stores
    __syncthreads();
    if (tid == 0) {
        unsigned long long t = atomicAdd(&g_bar, 1ULL);           // device scope
        unsigned long long target = (t / GRID + 1ULL) * GRID;     // end of this epoch
        while (__hip_atomic_load(&g_bar, __ATOMIC_RELAXED, __HIP_MEMORY_SCOPE_AGENT) < target)
            __builtin_amdgcn_s_sleep(8);
    }
    __syncthreads();
    __threadfence();                       // acquire: see other XCDs' xb stores

    // ---------------- two 32-row tiles: gather + MFMA + bias + ReLU ---------------
    #pragma unroll 1
    for (int tt = 0; tt < 2; ++tt) {
        const int n0   = chunk * 64 + tt * 32;
        const int row0 = b * NNODE + n0;

        // Phase A: gather + sum -> h_s (bf16)
        {
            const int r  = tid >> 3;       // row within tile, 0..31
            const int q  = tid & 7;        // channel slice, 16 ch each
            const int n  = n0 + r;
            const int c0 = q * 16;
            const int* ip = eidx + ((size_t)b * NNODE + n) * KNBR;   // plane 0

            int js[KNBR];
            #pragma unroll
            for (int p = 0; p < 4; ++p) {
                i32x4 jv = __builtin_nontemporal_load((const i32x4*)(ip + p * 4));
                js[p*4+0]=jv.x; js[p*4+1]=jv.y; js[p*4+2]=jv.z; js[p*4+3]=jv.w;
            }

            const ushort* xbb = xb + (size_t)b * NNODE * CIN;
            const ushort* xs  = xbb + (size_t)n * CIN + c0;
            short8 s0 = *(const short8*)xs, s1 = *(const short8*)(xs + 8);

            // 32 x 16B gather loads in flight before any accumulation.
            short8 t0[KNBR], t1[KNBR];
            #pragma unroll
            for (int k = 0; k < KNBR; ++k) {
                const ushort* xn = xbb + (size_t)js[k] * CIN + c0;
                t0[k] = *(const short8*)xn;
                t1[k] = *(const short8*)(xn + 8);
            }

            float acc[16];
            #pragma unroll
            for (int e = 0; e < 8; ++e) {
                acc[e]     = eps1 * bf16_f32(s0[e]);
                acc[8 + e] = eps1 * bf16_f32(s1[e]);
            }
            #pragma unroll
            for (int k = 0; k < KNBR; ++k) {
                #pragma unroll
                for (int e = 0; e < 8; ++e) {
                    acc[e]     += bf16_f32(t0[k][e]);
                    acc[8 + e] += bf16_f32(t1[k][e]);
                }
            }

            short* hp = h_s + r * HS_STRIDE + c0;
            #pragma unroll
            for (int p = 0; p < 2; ++p) {
                short8 s;
                #pragma unroll
                for (int e = 0; e < 8; ++e) s[e] = bf16_rne(acc[p*8+e]);
                *(short8*)(hp + p * 8) = s;
            }
        }

        __syncthreads();

        // Phase B: MFMA GEMM + bias + ReLU
        float* outb = out + (size_t)row0 * COUT;
        #pragma unroll
        for (int rt = 0; rt < 2; ++rt) {
            const short* ap = h_s + (rt * 16 + l16) * HS_STRIDE + lq * 8;
            short8 afrag[4];
            #pragma unroll
            for (int kb = 0; kb < 4; ++kb)
                afrag[kb] = *(const short8*)(ap + kb * 32);

            #pragma unroll
            for (int t = 0; t < 2; ++t) {
                f32x4 acc = { 0.f, 0.f, 0.f, 0.f };
                #pragma unroll
                for (int kb = 0; kb < 4; ++kb)
                    acc = __builtin_amdgcn_mfma_f32_16x16x32_bf16(afrag[kb], bfrag[t][kb], acc, 0, 0, 0);

                const float bv  = t ? bias1 : bias0;
                const int   col = wave * 32 + t * 16 + l16;
                #pragma unroll
                for (int ii = 0; ii < 4; ++ii) {
                    const int row = rt * 16 + lq * 4 + ii;   // C/D: row = quad*4 + reg
                    float v = acc[ii] + bv;
                    v = v > 0.f ? v : 0.f;
                    __builtin_nontemporal_store(v, &outb[(size_t)row * COUT + col]);
                }
            }
        }

        __syncthreads();   // h_s reused by next tile
    }
}

// ---------------- fallback (no workspace): fp32 fused single-kernel ----------------
__global__ __launch_bounds__(THREADS, 2)
void gin_fallback(const float* __restrict__ x, const int* __restrict__ eidx,
                  const float* __restrict__ W, const float* __restrict__ bias,
                  const float* __restrict__ epsp, float* __restrict__ out)
{
    __shared__ __align__(16) short h_s[32 * HS_STRIDE];
    const int tid = threadIdx.x;
    const int i   = blockIdx.x;
    const int xcd = i & 7, sub = i >> 3;
    const int b   = xcd >> 1;
    const int wbi = ((xcd & 1) << 7) | sub;
    const int n0  = wbi * 32;
    const int row0 = b * NNODE + n0;
    const float eps1 = 1.0f + epsp[0];
    {
        const int r = tid >> 3, q = tid & 7, n = n0 + r, c0 = q * 16;
        const int* ip = eidx + ((size_t)b * NNODE + n) * KNBR;
        int js[KNBR];
        #pragma unroll
        for (int p = 0; p < 4; ++p) {
            i32x4 jv = *(const i32x4*)(ip + p * 4);
            js[p*4+0]=jv.x; js[p*4+1]=jv.y; js[p*4+2]=jv.z; js[p*4+3]=jv.w;
        }
        float acc[16];
        const float* xbb = x + (size_t)b * NNODE * CIN;
        const float* xs  = xbb + (size_t)n * CIN + c0;
        #pragma unroll
        for (int p = 0; p < 4; ++p) {
            f32x4 v = *(const f32x4*)(xs + p * 4);
            acc[p*4+0]=eps1*v[0]; acc[p*4+1]=eps1*v[1]; acc[p*4+2]=eps1*v[2]; acc[p*4+3]=eps1*v[3];
        }
        #pragma unroll
        for (int k = 0; k < KNBR; ++k) {
            const float* xn = xbb + (size_t)js[k] * CIN + c0;
            #pragma unroll
            for (int p = 0; p < 4; ++p) {
                f32x4 v = *(const f32x4*)(xn + p * 4);
                acc[p*4+0]+=v[0]; acc[p*4+1]+=v[1]; acc[p*4+2]+=v[2]; acc[p*4+3]+=v[3];
            }
        }
        short* hp = h_s + r * HS_STRIDE + c0;
        #pragma unroll
        for (int p = 0; p < 2; ++p) {
            short8 s;
            #pragma unroll
            for (int e = 0; e < 8; ++e) s[e] = bf16_rne(acc[p*8+e]);
            *(short8*)(hp + p * 8) = s;
        }
    }
    const int wave = tid >> 6, lane = tid & 63, l16 = lane & 15, lq = lane >> 4;
    short8 bfrag[2][4];
    #pragma unroll
    for (int t = 0; t < 2; ++t) {
        const float* wp = W + (size_t)(wave * 32 + t * 16 + l16) * CIN;
        #pragma unroll
        for (int kb = 0; kb < 4; ++kb) {
            const float* wq = wp + kb * 32 + lq * 8;
            f32x4 f0 = *(const f32x4*)(wq);
            f32x4 f1 = *(const f32x4*)(wq + 4);
            short8 s;
            s[0]=bf16_rne(f0[0]); s[1]=bf16_rne(f0[1]); s[2]=bf16_rne(f0[2]); s[3]=bf16_rne(f0[3]);
            s[4]=bf16_rne(f1[0]); s[5]=bf16_rne(f1[1]); s[6]=bf16_rne(f1[2]); s[7]=bf16_rne(f1[3]);
            bfrag[t][kb] = s;
        }
    }
    const float bias0 = bias[wave * 32 + l16];
    const float bias1 = bias[wave * 32 + 16 + l16];
    __syncthreads();
    float* outb = out + (size_t)row0 * COUT;
    #pragma unroll
    for (int rt = 0; rt < 2; ++rt) {
        const short* ap = h_s + (rt * 16 + l16) * HS_STRIDE + lq * 8;
        short8 afrag[4];
        #pragma unroll
        for (int kb = 0; kb < 4; ++kb) afrag[kb] = *(const short8*)(ap + kb * 32);
        #pragma unroll
        for (int t = 0; t < 2; ++t) {
            f32x4 acc = { 0.f, 0.f, 0.f, 0.f };
            #pragma unroll
            for (int kb = 0; kb < 4; ++kb)
                acc = __builtin_amdgcn_mfma_f32_16x16x32_bf16(afrag[kb], bfrag[t][kb], acc, 0, 0, 0);
            const float bv = t ? bias1 : bias0;
            const int col = wave * 32 + t * 16 + l16;
            #pragma unroll
            for (int ii = 0; ii < 4; ++ii) {
                const int row = rt * 16 + lq * 4 + ii;
                float v = acc[ii] + bv;
                outb[(size_t)row * COUT + col] = v > 0.f ? v : 0.f;
            }
        }
    }
}

extern "C" void kernel_launch(void* const* d_in, const int* in_sizes, int n_in,
                              void* d_out, int out_size, void* d_ws, size_t ws_size,
                              hipStream_t stream) {
    const float* x    = (const float*)d_in[0];
    const int*   eidx = (const int*)d_in[1];
    const float* W    = (const float*)d_in[2];
    const float* bias = (const float*)d_in[3];
    const float* eps  = (const float*)d_in[4];
    float*       out  = (float*)d_out;

    const size_t need = (size_t)XELEM * sizeof(ushort);  // 8 MiB bf16 staging

    if (ws_size >= need) {
        ushort* xb = (ushort*)d_ws;
        gin_mono<<<dim3(GRID), dim3(THREADS), 0, stream>>>(x, eidx, W, bias, eps, xb, out);
    } else {
        gin_fallback<<<dim3((BATCH * NNODE) / 32), dim3(THREADS), 0, stream>>>(x, eidx, W, bias, eps, out);
    }
}

// Round 10
// 100.174 us; speedup vs baseline: 2.2580x; 2.2580x over previous
//
#include <hip/hip_runtime.h>
#include <stdint.h>

// GINConv1d: B=4, N=8192, K=16, C_IN=C_OUT=128
//
// R9: resubmit (infra failure, bench never ran). R8 fix: 256 threads = 4 waves;
// each wave owns 8 rows so all 32 h_s rows are written.
// Experiment: wave-wide row gather. One instr per (row, neighbor): 64 lanes x
// 4B = full 256B row = 2 cache-line touches vs R4's 4 per row. If the TA cost
// is per merged line-request, gather halves; if per lane-request, it
// quadruples (decisive between the two floor models).
#define BATCH   4
#define NNODE   8192
#define KNBR    16
#define CIN     128
#define COUT    128
#define MB      32          // rows (nodes) per block -> 1024 blocks
#define THREADS 256
#define HS_STRIDE 136       // shorts per h_s row: 128 + 8 pad

#define XELEM   (BATCH * NNODE * CIN)          // 4194304 fp32 elements
#define WELEM   (COUT * CIN)                   // 16384 fp32 elements
#define CVT_XBLK (XELEM / (256 * 8))           // 2048 blocks for x
#define CVT_WBLK (WELEM / (256 * 8))           // 8 blocks for W

typedef __attribute__((ext_vector_type(8))) short short8;   // 8 bf16 (MFMA A/B frag)
typedef __attribute__((ext_vector_type(4))) float f32x4;
typedef __attribute__((ext_vector_type(4))) int   i32x4;

__device__ __forceinline__ short bf16_rne(float f) {
    union { float f; uint32_t u; } v; v.f = f;
    return (short)((v.u + 0x7FFFu + ((v.u >> 16) & 1u)) >> 16);  // round-to-nearest-even
}
__device__ __forceinline__ float bf16_f32(short s) {
    union { uint32_t u; float f; } v; v.u = ((uint32_t)(uint16_t)s) << 16;
    return v.f;
}
// low/high bf16 of a packed dword -> fp32
__device__ __forceinline__ float bf16_lo(uint32_t u) {
    union { uint32_t u; float f; } v; v.u = u << 16;  return v.f;
}
__device__ __forceinline__ float bf16_hi(uint32_t u) {
    union { uint32_t u; float f; } v; v.u = u & 0xFFFF0000u; return v.f;
}

// ---------------- prepass: {x, W} fp32 -> bf16 in workspace ------------------------
__global__ __launch_bounds__(256)
void cvt_bf16(const float* __restrict__ x, const float* __restrict__ W,
              ushort* __restrict__ xb) {
    const int bi = blockIdx.x;
    const float* src;
    ushort*      dst;
    int          gid;
    if (bi < CVT_XBLK) { src = x; dst = xb;          gid = bi * 256 + threadIdx.x; }
    else               { src = W; dst = xb + XELEM;  gid = (bi - CVT_XBLK) * 256 + threadIdx.x; }
    const f32x4* xp = (const f32x4*)src + (size_t)gid * 2;
    f32x4 a = __builtin_nontemporal_load(xp);        // fp32 source is dead after this
    f32x4 c = __builtin_nontemporal_load(xp + 1);
    short8 s;
    s[0]=bf16_rne(a[0]); s[1]=bf16_rne(a[1]); s[2]=bf16_rne(a[2]); s[3]=bf16_rne(a[3]);
    s[4]=bf16_rne(c[0]); s[5]=bf16_rne(c[1]); s[6]=bf16_rne(c[2]); s[7]=bf16_rne(c[3]);
    ((short8*)dst)[gid] = s;
}

// ---------------- fused gather + eps-residual + MFMA GEMM + bias + ReLU ------------
template<bool USEBF>
__global__ __launch_bounds__(THREADS, 2)
void gin_fused(const float*  __restrict__ x,      // [B,N,CIN] fp32
               const ushort* __restrict__ xb,     // [B,N,CIN] bf16 (if USEBF)
               const ushort* __restrict__ wb,     // [COUT,CIN] bf16 (if USEBF)
               const int*    __restrict__ eidx,   // [2,B,N,K] int32; plane 0 = source idx
               const float*  __restrict__ W,      // [COUT,CIN] fp32
               const float*  __restrict__ bias,   // [COUT] fp32
               const float*  __restrict__ epsp,   // [1] fp32
               float*        __restrict__ out)    // [B,N,COUT] fp32
{
    __shared__ __align__(16) short h_s[MB * HS_STRIDE];

    const int tid = threadIdx.x;
    // XCD-locality swizzle: blockIdx -> XCD round-robin (i & 7). Pin batch b to
    // XCDs {2b,2b+1} so each XCD's gather set = one batch (2 MiB bf16) -> L2-resident.
    const int i   = blockIdx.x;            // 0..1023
    const int xcd = i & 7;
    const int sub = i >> 3;                // 0..127
    const int b   = xcd >> 1;              // batch 0..3
    const int wbi = ((xcd & 1) << 7) | sub;// 0..255 within batch
    const int n0  = wbi * MB;
    const int row0 = b * NNODE + n0;

    const float eps1 = 1.0f + epsp[0];

    // ---------------- Phase A: gather + sum -> h_s (bf16) --------------------------
    if constexpr (USEBF) {
        // Wave-wide row gather: one instr per (row, neighbor), 64 lanes x 4B
        // = full 256B row = 2 cache-line touches (R4 layout: 4 per row).
        // 4 waves x 8 rows = all 32 rows of the tile.
        const int wv = tid >> 6;           // wave 0..3: owns rows 8wv..8wv+7
        const int ln = tid & 63;
        const ushort* xbb = xb + (size_t)b * NNODE * CIN;

        uint32_t t[8][KNBR];               // 128 loads in flight, 1 VGPR each
        #pragma unroll
        for (int rr = 0; rr < 8; ++rr) {
            const int n = n0 + wv * 8 + rr;
            const int* ip = eidx + ((size_t)b * NNODE + n) * KNBR;   // plane 0
            int js[KNBR];
            #pragma unroll
            for (int p = 0; p < 4; ++p) {
                // wave-uniform broadcast load (all lanes same address: 1 line)
                i32x4 jv = __builtin_nontemporal_load((const i32x4*)(ip + p * 4));
                js[p*4+0]=jv.x; js[p*4+1]=jv.y; js[p*4+2]=jv.z; js[p*4+3]=jv.w;
            }
            #pragma unroll
            for (int k = 0; k < KNBR; ++k)
                t[rr][k] = *(const uint32_t*)(xbb + (size_t)js[k] * CIN + ln * 2);
        }

        #pragma unroll
        for (int rr = 0; rr < 8; ++rr) {
            const int n = n0 + wv * 8 + rr;
            uint32_t own = *(const uint32_t*)(xbb + (size_t)n * CIN + ln * 2);
            float lo = eps1 * bf16_lo(own);
            float hi = eps1 * bf16_hi(own);
            #pragma unroll
            for (int k = 0; k < KNBR; ++k) {
                lo += bf16_lo(t[rr][k]);
                hi += bf16_hi(t[rr][k]);
            }
            uint32_t packed = (uint32_t)(uint16_t)bf16_rne(lo)
                            | ((uint32_t)(uint16_t)bf16_rne(hi) << 16);
            // lane ln -> dword at row (wv*8+rr), channels {2ln, 2ln+1}:
            // consecutive dwords, 2 lanes/bank alias = conflict-free
            *(uint32_t*)(h_s + (size_t)(wv * 8 + rr) * HS_STRIDE + ln * 2) = packed;
        }
    } else {
        const int r  = tid >> 3;           // row within block, 0..31
        const int q  = tid & 7;            // channel slice, 16 ch each
        const int n  = n0 + r;
        const int c0 = q * 16;
        const int* ip = eidx + ((size_t)b * NNODE + n) * KNBR;   // plane 0

        int js[KNBR];
        #pragma unroll
        for (int p = 0; p < 4; ++p) {
            i32x4 jv = *(const i32x4*)(ip + p * 4);
            js[p*4+0]=jv.x; js[p*4+1]=jv.y; js[p*4+2]=jv.z; js[p*4+3]=jv.w;
        }
        float acc[16];
        const float* xbb = x + (size_t)b * NNODE * CIN;
        const float* xs  = xbb + (size_t)n * CIN + c0;
        #pragma unroll
        for (int p = 0; p < 4; ++p) {
            f32x4 v = *(const f32x4*)(xs + p * 4);
            acc[p*4+0]=eps1*v[0]; acc[p*4+1]=eps1*v[1]; acc[p*4+2]=eps1*v[2]; acc[p*4+3]=eps1*v[3];
        }
        #pragma unroll
        for (int k = 0; k < KNBR; ++k) {
            const float* xn = xbb + (size_t)js[k] * CIN + c0;
            #pragma unroll
            for (int p = 0; p < 4; ++p) {
                f32x4 v = *(const f32x4*)(xn + p * 4);
                acc[p*4+0]+=v[0]; acc[p*4+1]+=v[1]; acc[p*4+2]+=v[2]; acc[p*4+3]+=v[3];
            }
        }
        short* hp = h_s + r * HS_STRIDE + c0;
        #pragma unroll
        for (int p = 0; p < 2; ++p) {
            short8 s;
            #pragma unroll
            for (int e = 0; e < 8; ++e) s[e] = bf16_rne(acc[p*8+e]);
            *(short8*)(hp + p * 8) = s;
        }
    }

    // ---------------- W -> bf16 B-fragments in registers (per-wave 32-out slice) ---
    const int wave = tid >> 6;
    const int lane = tid & 63;
    const int l16  = lane & 15;
    const int lq   = lane >> 4;            // quad 0..3

    short8 bfrag[2][4];                    // [o_tile][kb]: B[k][n]=W[o][c], n=l16, k=lq*8+j
    if constexpr (USEBF) {
        #pragma unroll
        for (int t = 0; t < 2; ++t) {
            const ushort* wp = wb + (size_t)(wave * 32 + t * 16 + l16) * CIN;
            #pragma unroll
            for (int kb = 0; kb < 4; ++kb)
                bfrag[t][kb] = *(const short8*)(wp + kb * 32 + lq * 8);
        }
    } else {
        #pragma unroll
        for (int t = 0; t < 2; ++t) {
            const float* wp = W + (size_t)(wave * 32 + t * 16 + l16) * CIN;
            #pragma unroll
            for (int kb = 0; kb < 4; ++kb) {
                const float* wq = wp + kb * 32 + lq * 8;
                f32x4 f0 = *(const f32x4*)(wq);
                f32x4 f1 = *(const f32x4*)(wq + 4);
                short8 s;
                s[0]=bf16_rne(f0[0]); s[1]=bf16_rne(f0[1]); s[2]=bf16_rne(f0[2]); s[3]=bf16_rne(f0[3]);
                s[4]=bf16_rne(f1[0]); s[5]=bf16_rne(f1[1]); s[6]=bf16_rne(f1[2]); s[7]=bf16_rne(f1[3]);
                bfrag[t][kb] = s;
            }
        }
    }
    const float bias0 = bias[wave * 32 + l16];
    const float bias1 = bias[wave * 32 + 16 + l16];

    __syncthreads();

    // ---------------- Phase B: MFMA GEMM + bias + ReLU -----------------------------
    float* outb = out + (size_t)row0 * COUT;
    #pragma unroll
    for (int rt = 0; rt < MB / 16; ++rt) {
        const short* ap = h_s + (rt * 16 + l16) * HS_STRIDE + lq * 8;
        short8 afrag[4];
        #pragma unroll
        for (int kb = 0; kb < 4; ++kb)
            afrag[kb] = *(const short8*)(ap + kb * 32);

        #pragma unroll
        for (int t = 0; t < 2; ++t) {
            f32x4 acc = { 0.f, 0.f, 0.f, 0.f };
            #pragma unroll
            for (int kb = 0; kb < 4; ++kb)
                acc = __builtin_amdgcn_mfma_f32_16x16x32_bf16(afrag[kb], bfrag[t][kb], acc, 0, 0, 0);

            const float bv  = t ? bias1 : bias0;
            const int   col = wave * 32 + t * 16 + l16;
            #pragma unroll
            for (int ii = 0; ii < 4; ++ii) {
                const int row = rt * 16 + lq * 4 + ii;   // C/D: row = quad*4 + reg
                float v = acc[ii] + bv;
                v = v > 0.f ? v : 0.f;
                // nt store: the 16 MiB out stream must not evict the bf16 gather set
                __builtin_nontemporal_store(v, &outb[(size_t)row * COUT + col]);
            }
        }
    }
}

extern "C" void kernel_launch(void* const* d_in, const int* in_sizes, int n_in,
                              void* d_out, int out_size, void* d_ws, size_t ws_size,
                              hipStream_t stream) {
    const float* x    = (const float*)d_in[0];
    const int*   eidx = (const int*)d_in[1];
    const float* W    = (const float*)d_in[2];
    const float* bias = (const float*)d_in[3];
    const float* eps  = (const float*)d_in[4];
    float*       out  = (float*)d_out;

    const size_t need = (size_t)(XELEM + WELEM) * sizeof(ushort);  // 8 MiB + 32 KiB
    dim3 grid((BATCH * NNODE) / MB);   // 1024 blocks

    if (ws_size >= need) {
        ushort* xb = (ushort*)d_ws;
        cvt_bf16<<<dim3(CVT_XBLK + CVT_WBLK), dim3(256), 0, stream>>>(x, W, xb);
        gin_fused<true><<<grid, dim3(THREADS), 0, stream>>>(x, xb, xb + XELEM, eidx, W, bias, eps, out);
    } else {
        gin_fused<false><<<grid, dim3(THREADS), 0, stream>>>(x, nullptr, nullptr, eidx, W, bias, eps, out);
    }
}

// Round 11
// 91.851 us; speedup vs baseline: 2.4626x; 1.0906x over previous
//
#include <hip/hip_runtime.h>
#include <stdint.h>

// GINConv1d: B=4, N=8192, K=16, C_IN=C_OUT=128
//
// R10 post-mortem: wave-wide (64x4B) gather = 100.2 us vs R4's 94.96 -> cost
// scales with lane-requests; 16B/lane is the minimum (16 lane-req per 256B row).
// R11: same lane-request count as R4, but HALF the line-touches: thread q
// covers bytes [q*16, q*16+16) (line 0) and [128+q*16, ...) (line 1) instead of
// R4's 32B-strided pair that touches both lines twice. t0 instr: 8 rows x 1
// line; t1: 8 rows x 1 line -> 2 line-touches/row (R4: 4). If L1 tag-lookups
// bound the gather, it halves; if lane-request-bound, neutral -> roofline.
#define BATCH   4
#define NNODE   8192
#define KNBR    16
#define CIN     128
#define COUT    128
#define MB      32          // rows (nodes) per block -> 1024 blocks
#define THREADS 256
#define HS_STRIDE 136       // shorts per h_s row: 128 + 8 pad

#define XELEM   (BATCH * NNODE * CIN)          // 4194304 fp32 elements
#define WELEM   (COUT * CIN)                   // 16384 fp32 elements
#define CVT_XBLK (XELEM / (256 * 8))           // 2048 blocks for x
#define CVT_WBLK (WELEM / (256 * 8))           // 8 blocks for W

typedef __attribute__((ext_vector_type(8))) short short8;   // 8 bf16 (MFMA A/B frag)
typedef __attribute__((ext_vector_type(4))) float f32x4;
typedef __attribute__((ext_vector_type(4))) int   i32x4;

__device__ __forceinline__ short bf16_rne(float f) {
    union { float f; uint32_t u; } v; v.f = f;
    return (short)((v.u + 0x7FFFu + ((v.u >> 16) & 1u)) >> 16);  // round-to-nearest-even
}
__device__ __forceinline__ float bf16_f32(short s) {
    union { uint32_t u; float f; } v; v.u = ((uint32_t)(uint16_t)s) << 16;
    return v.f;
}

// ---------------- prepass: {x, W} fp32 -> bf16 in workspace ------------------------
__global__ __launch_bounds__(256)
void cvt_bf16(const float* __restrict__ x, const float* __restrict__ W,
              ushort* __restrict__ xb) {
    const int bi = blockIdx.x;
    const float* src;
    ushort*      dst;
    int          gid;
    if (bi < CVT_XBLK) { src = x; dst = xb;          gid = bi * 256 + threadIdx.x; }
    else               { src = W; dst = xb + XELEM;  gid = (bi - CVT_XBLK) * 256 + threadIdx.x; }
    const f32x4* xp = (const f32x4*)src + (size_t)gid * 2;
    f32x4 a = __builtin_nontemporal_load(xp);        // fp32 source is dead after this
    f32x4 c = __builtin_nontemporal_load(xp + 1);
    short8 s;
    s[0]=bf16_rne(a[0]); s[1]=bf16_rne(a[1]); s[2]=bf16_rne(a[2]); s[3]=bf16_rne(a[3]);
    s[4]=bf16_rne(c[0]); s[5]=bf16_rne(c[1]); s[6]=bf16_rne(c[2]); s[7]=bf16_rne(c[3]);
    ((short8*)dst)[gid] = s;
}

// ---------------- fused gather + eps-residual + MFMA GEMM + bias + ReLU ------------
// launch_bounds(256,2): VGPR cap 256 so all 32 neighbor prefetch loads (128 data
// VGPRs) stay in flight without spilling.
template<bool USEBF>
__global__ __launch_bounds__(THREADS, 2)
void gin_fused(const float*  __restrict__ x,      // [B,N,CIN] fp32
               const ushort* __restrict__ xb,     // [B,N,CIN] bf16 (if USEBF)
               const ushort* __restrict__ wb,     // [COUT,CIN] bf16 (if USEBF)
               const int*    __restrict__ eidx,   // [2,B,N,K] int32; plane 0 = source idx
               const float*  __restrict__ W,      // [COUT,CIN] fp32
               const float*  __restrict__ bias,   // [COUT] fp32
               const float*  __restrict__ epsp,   // [1] fp32
               float*        __restrict__ out)    // [B,N,COUT] fp32
{
    __shared__ __align__(16) short h_s[MB * HS_STRIDE];

    const int tid = threadIdx.x;
    // XCD-locality swizzle: blockIdx -> XCD round-robin (i & 7). Pin batch b to
    // XCDs {2b,2b+1} so each XCD's gather set = one batch (2 MiB bf16) -> L2-resident.
    const int i   = blockIdx.x;            // 0..1023
    const int xcd = i & 7;
    const int sub = i >> 3;                // 0..127
    const int b   = xcd >> 1;              // batch 0..3
    const int wbi = ((xcd & 1) << 7) | sub;// 0..255 within batch
    const int n0  = wbi * MB;
    const int row0 = b * NNODE + n0;

    const float eps1 = 1.0f + epsp[0];

    // ---------------- Phase A: gather + sum -> h_s (bf16) --------------------------
    {
        const int r  = tid >> 3;           // row within block, 0..31
        const int q  = tid & 7;            // slice index, 0..7
        const int n  = n0 + r;
        // Line-split slices: A = shorts [q*8, q*8+8)   -> bytes [q*16, +16): LINE 0
        //                    B = shorts [64+q*8, ...)  -> bytes [128+q*16): LINE 1
        // Each gather wave-instr touches 8 lines (one per row), not 16.
        const int cA = q * 8;
        const int cB = 64 + q * 8;
        const int* ip = eidx + ((size_t)b * NNODE + n) * KNBR;   // plane 0

        int js[KNBR];
        #pragma unroll
        for (int p = 0; p < 4; ++p) {
            i32x4 jv = __builtin_nontemporal_load((const i32x4*)(ip + p * 4));
            js[p*4+0]=jv.x; js[p*4+1]=jv.y; js[p*4+2]=jv.z; js[p*4+3]=jv.w;
        }

        float acc[16];

        if constexpr (USEBF) {
            const ushort* xbb = xb + (size_t)b * NNODE * CIN;
            const ushort* xs  = xbb + (size_t)n * CIN;
            short8 s0 = *(const short8*)(xs + cA), s1 = *(const short8*)(xs + cB);

            // Prefetch ALL 16 neighbor slices into registers (32 x 16B loads in
            // flight per thread) BEFORE any accumulation -> memory-level parallelism.
            short8 t0[KNBR], t1[KNBR];
            #pragma unroll
            for (int k = 0; k < KNBR; ++k) {
                const ushort* xn = xbb + (size_t)js[k] * CIN;
                t0[k] = *(const short8*)(xn + cA);
                t1[k] = *(const short8*)(xn + cB);
            }

            #pragma unroll
            for (int e = 0; e < 8; ++e) {
                acc[e]     = eps1 * bf16_f32(s0[e]);
                acc[8 + e] = eps1 * bf16_f32(s1[e]);
            }
            #pragma unroll
            for (int k = 0; k < KNBR; ++k) {
                #pragma unroll
                for (int e = 0; e < 8; ++e) {
                    acc[e]     += bf16_f32(t0[k][e]);
                    acc[8 + e] += bf16_f32(t1[k][e]);
                }
            }
        } else {
            const float* xbb = x + (size_t)b * NNODE * CIN;
            const float* xs  = xbb + (size_t)n * CIN;
            #pragma unroll
            for (int p = 0; p < 2; ++p) {
                f32x4 v0 = *(const f32x4*)(xs + (p ? cB : cA) + 0);
                f32x4 v1 = *(const f32x4*)(xs + (p ? cB : cA) + 4);
                #pragma unroll
                for (int e = 0; e < 4; ++e) {
                    acc[p*8+e]   = eps1 * v0[e];
                    acc[p*8+4+e] = eps1 * v1[e];
                }
            }
            #pragma unroll
            for (int k = 0; k < KNBR; ++k) {
                const float* xn = xbb + (size_t)js[k] * CIN;
                #pragma unroll
                for (int p = 0; p < 2; ++p) {
                    f32x4 v0 = *(const f32x4*)(xn + (p ? cB : cA) + 0);
                    f32x4 v1 = *(const f32x4*)(xn + (p ? cB : cA) + 4);
                    #pragma unroll
                    for (int e = 0; e < 4; ++e) {
                        acc[p*8+e]   += v0[e];
                        acc[p*8+4+e] += v1[e];
                    }
                }
            }
        }

        short* hp = h_s + r * HS_STRIDE;
        {
            short8 sA, sB;
            #pragma unroll
            for (int e = 0; e < 8; ++e) {
                sA[e] = bf16_rne(acc[e]);
                sB[e] = bf16_rne(acc[8 + e]);
            }
            *(short8*)(hp + cA) = sA;
            *(short8*)(hp + cB) = sB;
        }
    }

    // ---------------- W -> bf16 B-fragments in registers (per-wave 32-out slice) ---
    const int wave = tid >> 6;
    const int lane = tid & 63;
    const int l16  = lane & 15;
    const int lq   = lane >> 4;            // quad 0..3

    short8 bfrag[2][4];                    // [o_tile][kb]: B[k][n]=W[o][c], n=l16, k=lq*8+j
    if constexpr (USEBF) {
        #pragma unroll
        for (int t = 0; t < 2; ++t) {
            const ushort* wp = wb + (size_t)(wave * 32 + t * 16 + l16) * CIN;
            #pragma unroll
            for (int kb = 0; kb < 4; ++kb)
                bfrag[t][kb] = *(const short8*)(wp + kb * 32 + lq * 8);
        }
    } else {
        #pragma unroll
        for (int t = 0; t < 2; ++t) {
            const float* wp = W + (size_t)(wave * 32 + t * 16 + l16) * CIN;
            #pragma unroll
            for (int kb = 0; kb < 4; ++kb) {
                const float* wq = wp + kb * 32 + lq * 8;
                f32x4 f0 = *(const f32x4*)(wq);
                f32x4 f1 = *(const f32x4*)(wq + 4);
                short8 s;
                s[0]=bf16_rne(f0[0]); s[1]=bf16_rne(f0[1]); s[2]=bf16_rne(f0[2]); s[3]=bf16_rne(f0[3]);
                s[4]=bf16_rne(f1[0]); s[5]=bf16_rne(f1[1]); s[6]=bf16_rne(f1[2]); s[7]=bf16_rne(f1[3]);
                bfrag[t][kb] = s;
            }
        }
    }
    const float bias0 = bias[wave * 32 + l16];
    const float bias1 = bias[wave * 32 + 16 + l16];

    __syncthreads();

    // ---------------- Phase B: MFMA GEMM + bias + ReLU -----------------------------
    float* outb = out + (size_t)row0 * COUT;
    #pragma unroll
    for (int rt = 0; rt < MB / 16; ++rt) {
        const short* ap = h_s + (rt * 16 + l16) * HS_STRIDE + lq * 8;
        short8 afrag[4];
        #pragma unroll
        for (int kb = 0; kb < 4; ++kb)
            afrag[kb] = *(const short8*)(ap + kb * 32);

        #pragma unroll
        for (int t = 0; t < 2; ++t) {
            f32x4 acc = { 0.f, 0.f, 0.f, 0.f };
            #pragma unroll
            for (int kb = 0; kb < 4; ++kb)
                acc = __builtin_amdgcn_mfma_f32_16x16x32_bf16(afrag[kb], bfrag[t][kb], acc, 0, 0, 0);

            const float bv  = t ? bias1 : bias0;
            const int   col = wave * 32 + t * 16 + l16;
            #pragma unroll
            for (int ii = 0; ii < 4; ++ii) {
                const int row = rt * 16 + lq * 4 + ii;   // C/D: row = quad*4 + reg
                float v = acc[ii] + bv;
                v = v > 0.f ? v : 0.f;
                // nt store: the 16 MiB out stream must not evict the bf16 gather set
                __builtin_nontemporal_store(v, &outb[(size_t)row * COUT + col]);
            }
        }
    }
}

extern "C" void kernel_launch(void* const* d_in, const int* in_sizes, int n_in,
                              void* d_out, int out_size, void* d_ws, size_t ws_size,
                              hipStream_t stream) {
    const float* x    = (const float*)d_in[0];
    const int*   eidx = (const int*)d_in[1];
    const float* W    = (const float*)d_in[2];
    const float* bias = (const float*)d_in[3];
    const float* eps  = (const float*)d_in[4];
    float*       out  = (float*)d_out;

    const size_t need = (size_t)(XELEM + WELEM) * sizeof(ushort);  // 8 MiB + 32 KiB
    dim3 grid((BATCH * NNODE) / MB);   // 1024 blocks

    if (ws_size >= need) {
        ushort* xb = (ushort*)d_ws;
        cvt_bf16<<<dim3(CVT_XBLK + CVT_WBLK), dim3(256), 0, stream>>>(x, W, xb);
        gin_fused<true><<<grid, dim3(THREADS), 0, stream>>>(x, xb, xb + XELEM, eidx, W, bias, eps, out);
    } else {
        gin_fused<false><<<grid, dim3(THREADS), 0, stream>>>(x, nullptr, nullptr, eidx, W, bias, eps, out);
    }
}

// Round 12
// 90.179 us; speedup vs baseline: 2.5083x; 1.0185x over previous
//
#include <hip/hip_runtime.h>
#include <stdint.h>

// GINConv1d: B=4, N=8192, K=16, C_IN=C_OUT=128
//
// R11 (91.85, best): line-split gather confirmed line-touch cost (~1.5us/LT-row);
// data gather now at min (16 lane-req, 2 line-touches per row). R12: the last
// un-minimized VMEM term — index loads are 8x redundant (8 threads/row load the
// same 64B): 32 lane-req/row, 2x the data gather. Stage indices via LDS once
// (256 x int2 coalesced = 2 lane-req/row), broadcast-read from LDS (free).
#define BATCH   4
#define NNODE   8192
#define KNBR    16
#define CIN     128
#define COUT    128
#define MB      32          // rows (nodes) per block -> 1024 blocks
#define THREADS 256
#define HS_STRIDE 136       // shorts per h_s row: 128 + 8 pad

#define XELEM   (BATCH * NNODE * CIN)          // 4194304 fp32 elements
#define WELEM   (COUT * CIN)                   // 16384 fp32 elements
#define CVT_XBLK (XELEM / (256 * 8))           // 2048 blocks for x
#define CVT_WBLK (WELEM / (256 * 8))           // 8 blocks for W

typedef __attribute__((ext_vector_type(8))) short short8;   // 8 bf16 (MFMA A/B frag)
typedef __attribute__((ext_vector_type(4))) float f32x4;
typedef __attribute__((ext_vector_type(4))) int   i32x4;
typedef __attribute__((ext_vector_type(2))) int   i32x2;

__device__ __forceinline__ short bf16_rne(float f) {
    union { float f; uint32_t u; } v; v.f = f;
    return (short)((v.u + 0x7FFFu + ((v.u >> 16) & 1u)) >> 16);  // round-to-nearest-even
}
__device__ __forceinline__ float bf16_f32(short s) {
    union { uint32_t u; float f; } v; v.u = ((uint32_t)(uint16_t)s) << 16;
    return v.f;
}

// ---------------- prepass: {x, W} fp32 -> bf16 in workspace ------------------------
__global__ __launch_bounds__(256)
void cvt_bf16(const float* __restrict__ x, const float* __restrict__ W,
              ushort* __restrict__ xb) {
    const int bi = blockIdx.x;
    const float* src;
    ushort*      dst;
    int          gid;
    if (bi < CVT_XBLK) { src = x; dst = xb;          gid = bi * 256 + threadIdx.x; }
    else               { src = W; dst = xb + XELEM;  gid = (bi - CVT_XBLK) * 256 + threadIdx.x; }
    const f32x4* xp = (const f32x4*)src + (size_t)gid * 2;
    f32x4 a = __builtin_nontemporal_load(xp);        // fp32 source is dead after this
    f32x4 c = __builtin_nontemporal_load(xp + 1);
    short8 s;
    s[0]=bf16_rne(a[0]); s[1]=bf16_rne(a[1]); s[2]=bf16_rne(a[2]); s[3]=bf16_rne(a[3]);
    s[4]=bf16_rne(c[0]); s[5]=bf16_rne(c[1]); s[6]=bf16_rne(c[2]); s[7]=bf16_rne(c[3]);
    ((short8*)dst)[gid] = s;
}

// ---------------- fused gather + eps-residual + MFMA GEMM + bias + ReLU ------------
// launch_bounds(256,2): VGPR cap 256 so all 32 neighbor prefetch loads (128 data
// VGPRs) stay in flight without spilling.
template<bool USEBF>
__global__ __launch_bounds__(THREADS, 2)
void gin_fused(const float*  __restrict__ x,      // [B,N,CIN] fp32
               const ushort* __restrict__ xb,     // [B,N,CIN] bf16 (if USEBF)
               const ushort* __restrict__ wb,     // [COUT,CIN] bf16 (if USEBF)
               const int*    __restrict__ eidx,   // [2,B,N,K] int32; plane 0 = source idx
               const float*  __restrict__ W,      // [COUT,CIN] fp32
               const float*  __restrict__ bias,   // [COUT] fp32
               const float*  __restrict__ epsp,   // [1] fp32
               float*        __restrict__ out)    // [B,N,COUT] fp32
{
    __shared__ __align__(16) short h_s[MB * HS_STRIDE];
    __shared__ __align__(16) int   idx_s[MB * KNBR];     // 2 KB

    const int tid = threadIdx.x;
    // XCD-locality swizzle: blockIdx -> XCD round-robin (i & 7). Pin batch b to
    // XCDs {2b,2b+1} so each XCD's gather set = one batch (2 MiB bf16) -> L2-resident.
    const int i   = blockIdx.x;            // 0..1023
    const int xcd = i & 7;
    const int sub = i >> 3;                // 0..127
    const int b   = xcd >> 1;              // batch 0..3
    const int wbi = ((xcd & 1) << 7) | sub;// 0..255 within batch
    const int n0  = wbi * MB;
    const int row0 = b * NNODE + n0;

    const float eps1 = 1.0f + epsp[0];

    // ---------------- Phase 0: stage block's indices via LDS (coalesced once) ------
    // 256 threads x int2 = 2 KB contiguous: 2 lane-req/row vs 32 for the old
    // 8x-redundant per-thread loads.
    {
        const i32x2* src = (const i32x2*)(eidx + ((size_t)b * NNODE + n0) * KNBR);
        i32x2 v = __builtin_nontemporal_load(src + tid);
        *(i32x2*)(idx_s + tid * 2) = v;
    }
    __syncthreads();

    // ---------------- Phase A: gather + sum -> h_s (bf16) --------------------------
    {
        const int r  = tid >> 3;           // row within block, 0..31
        const int q  = tid & 7;            // slice index, 0..7
        const int n  = n0 + r;
        // Line-split slices: A = shorts [q*8, q*8+8)   -> bytes [q*16, +16): LINE 0
        //                    B = shorts [64+q*8, ...)  -> bytes [128+q*16): LINE 1
        // Each gather wave-instr touches 8 lines (one per row), not 16.
        const int cA = q * 8;
        const int cB = 64 + q * 8;

        int js[KNBR];
        {
            // same-address across the 8 q-threads of a row -> LDS broadcast (free)
            const i32x4* jp = (const i32x4*)(idx_s + r * KNBR);
            #pragma unroll
            for (int p = 0; p < 4; ++p) {
                i32x4 jv = jp[p];
                js[p*4+0]=jv.x; js[p*4+1]=jv.y; js[p*4+2]=jv.z; js[p*4+3]=jv.w;
            }
        }

        float acc[16];

        if constexpr (USEBF) {
            const ushort* xbb = xb + (size_t)b * NNODE * CIN;
            const ushort* xs  = xbb + (size_t)n * CIN;
            short8 s0 = *(const short8*)(xs + cA), s1 = *(const short8*)(xs + cB);

            // Prefetch ALL 16 neighbor slices into registers (32 x 16B loads in
            // flight per thread) BEFORE any accumulation -> memory-level parallelism.
            short8 t0[KNBR], t1[KNBR];
            #pragma unroll
            for (int k = 0; k < KNBR; ++k) {
                const ushort* xn = xbb + (size_t)js[k] * CIN;
                t0[k] = *(const short8*)(xn + cA);
                t1[k] = *(const short8*)(xn + cB);
            }

            #pragma unroll
            for (int e = 0; e < 8; ++e) {
                acc[e]     = eps1 * bf16_f32(s0[e]);
                acc[8 + e] = eps1 * bf16_f32(s1[e]);
            }
            #pragma unroll
            for (int k = 0; k < KNBR; ++k) {
                #pragma unroll
                for (int e = 0; e < 8; ++e) {
                    acc[e]     += bf16_f32(t0[k][e]);
                    acc[8 + e] += bf16_f32(t1[k][e]);
                }
            }
        } else {
            const float* xbb = x + (size_t)b * NNODE * CIN;
            const float* xs  = xbb + (size_t)n * CIN;
            #pragma unroll
            for (int p = 0; p < 2; ++p) {
                f32x4 v0 = *(const f32x4*)(xs + (p ? cB : cA) + 0);
                f32x4 v1 = *(const f32x4*)(xs + (p ? cB : cA) + 4);
                #pragma unroll
                for (int e = 0; e < 4; ++e) {
                    acc[p*8+e]   = eps1 * v0[e];
                    acc[p*8+4+e] = eps1 * v1[e];
                }
            }
            #pragma unroll
            for (int k = 0; k < KNBR; ++k) {
                const float* xn = xbb + (size_t)js[k] * CIN;
                #pragma unroll
                for (int p = 0; p < 2; ++p) {
                    f32x4 v0 = *(const f32x4*)(xn + (p ? cB : cA) + 0);
                    f32x4 v1 = *(const f32x4*)(xn + (p ? cB : cA) + 4);
                    #pragma unroll
                    for (int e = 0; e < 4; ++e) {
                        acc[p*8+e]   += v0[e];
                        acc[p*8+4+e] += v1[e];
                    }
                }
            }
        }

        short* hp = h_s + r * HS_STRIDE;
        {
            short8 sA, sB;
            #pragma unroll
            for (int e = 0; e < 8; ++e) {
                sA[e] = bf16_rne(acc[e]);
                sB[e] = bf16_rne(acc[8 + e]);
            }
            *(short8*)(hp + cA) = sA;
            *(short8*)(hp + cB) = sB;
        }
    }

    // ---------------- W -> bf16 B-fragments in registers (per-wave 32-out slice) ---
    const int wave = tid >> 6;
    const int lane = tid & 63;
    const int l16  = lane & 15;
    const int lq   = lane >> 4;            // quad 0..3

    short8 bfrag[2][4];                    // [o_tile][kb]: B[k][n]=W[o][c], n=l16, k=lq*8+j
    if constexpr (USEBF) {
        #pragma unroll
        for (int t = 0; t < 2; ++t) {
            const ushort* wp = wb + (size_t)(wave * 32 + t * 16 + l16) * CIN;
            #pragma unroll
            for (int kb = 0; kb < 4; ++kb)
                bfrag[t][kb] = *(const short8*)(wp + kb * 32 + lq * 8);
        }
    } else {
        #pragma unroll
        for (int t = 0; t < 2; ++t) {
            const float* wp = W + (size_t)(wave * 32 + t * 16 + l16) * CIN;
            #pragma unroll
            for (int kb = 0; kb < 4; ++kb) {
                const float* wq = wp + kb * 32 + lq * 8;
                f32x4 f0 = *(const f32x4*)(wq);
                f32x4 f1 = *(const f32x4*)(wq + 4);
                short8 s;
                s[0]=bf16_rne(f0[0]); s[1]=bf16_rne(f0[1]); s[2]=bf16_rne(f0[2]); s[3]=bf16_rne(f0[3]);
                s[4]=bf16_rne(f1[0]); s[5]=bf16_rne(f1[1]); s[6]=bf16_rne(f1[2]); s[7]=bf16_rne(f1[3]);
                bfrag[t][kb] = s;
            }
        }
    }
    const float bias0 = bias[wave * 32 + l16];
    const float bias1 = bias[wave * 32 + 16 + l16];

    __syncthreads();

    // ---------------- Phase B: MFMA GEMM + bias + ReLU -----------------------------
    float* outb = out + (size_t)row0 * COUT;
    #pragma unroll
    for (int rt = 0; rt < MB / 16; ++rt) {
        const short* ap = h_s + (rt * 16 + l16) * HS_STRIDE + lq * 8;
        short8 afrag[4];
        #pragma unroll
        for (int kb = 0; kb < 4; ++kb)
            afrag[kb] = *(const short8*)(ap + kb * 32);

        #pragma unroll
        for (int t = 0; t < 2; ++t) {
            f32x4 acc = { 0.f, 0.f, 0.f, 0.f };
            #pragma unroll
            for (int kb = 0; kb < 4; ++kb)
                acc = __builtin_amdgcn_mfma_f32_16x16x32_bf16(afrag[kb], bfrag[t][kb], acc, 0, 0, 0);

            const float bv  = t ? bias1 : bias0;
            const int   col = wave * 32 + t * 16 + l16;
            #pragma unroll
            for (int ii = 0; ii < 4; ++ii) {
                const int row = rt * 16 + lq * 4 + ii;   // C/D: row = quad*4 + reg
                float v = acc[ii] + bv;
                v = v > 0.f ? v : 0.f;
                // nt store: the 16 MiB out stream must not evict the bf16 gather set
                __builtin_nontemporal_store(v, &outb[(size_t)row * COUT + col]);
            }
        }
    }
}

extern "C" void kernel_launch(void* const* d_in, const int* in_sizes, int n_in,
                              void* d_out, int out_size, void* d_ws, size_t ws_size,
                              hipStream_t stream) {
    const float* x    = (const float*)d_in[0];
    const int*   eidx = (const int*)d_in[1];
    const float* W    = (const float*)d_in[2];
    const float* bias = (const float*)d_in[3];
    const float* eps  = (const float*)d_in[4];
    float*       out  = (float*)d_out;

    const size_t need = (size_t)(XELEM + WELEM) * sizeof(ushort);  // 8 MiB + 32 KiB
    dim3 grid((BATCH * NNODE) / MB);   // 1024 blocks

    if (ws_size >= need) {
        ushort* xb = (ushort*)d_ws;
        cvt_bf16<<<dim3(CVT_XBLK + CVT_WBLK), dim3(256), 0, stream>>>(x, W, xb);
        gin_fused<true><<<grid, dim3(THREADS), 0, stream>>>(x, xb, xb + XELEM, eidx, W, bias, eps, out);
    } else {
        gin_fused<false><<<grid, dim3(THREADS), 0, stream>>>(x, nullptr, nullptr, eidx, W, bias, eps, out);
    }
}